// Round 5
// baseline (92.778 us; speedup 1.0000x reference)
//
#include <hip/hip_runtime.h>

#define HH 96
#define WW 96
#define NN (HH * WW)            // 9216
#define TILE 512                // i/j tile size
#define NT (NN / TILE)          // 18 tiles
#define NPAIRS (NT * (NT + 1) / 2)  // 171 tile-pairs (a <= b)
#define JSPLIT 16
#define JC (TILE / JSPLIT)      // 32 j's per block
#define BLK 256
#define M 2                     // i's per thread -> i-tile = M*BLK = 512

// Gaussian constants with log2(e) folded in (native v_exp_f32 is exp2):
// CXY  = log2(e) / (2 * 15^2),  CRGB = log2(e) / (2 * 0.125^2)
#define CXY 0.0032059890f
#define CRGB 46.16624131f

// arg_ij = Ai + Aj + yi*(2CXY*yj) + xi*(2CXY*xj) + ri*(2CRGB*rj) + gi*(2CRGB*gj) + bi*(2CRGB*bj)
// A_k = -CXY*(y^2+x^2) - CRGB*(r^2+g^2+b^2). All cross terms >= 0; the fma chain
// rises monotonically from Ai+Aj (>= -392) to <= 0: no overflow.
// Scalar form (NOT packed): R2/R3 showed packing regresses on this kernel.

__global__ __launch_bounds__(BLK) void crf_occ_kernel(
    const float* __restrict__ probs,   // [2, N], class-0 plane first
    const float* __restrict__ image,   // [3, N]
    float* __restrict__ out)           // [1], pre-zeroed
{
    __shared__ float4 sq1[JC];  // (2CXY*yj, 2CXY*xj, 2CRGB*rj, 2CRGB*gj)
    __shared__ float4 sq2[JC];  // (2CRGB*bj, Aj, aj, pad)

    // Decode tile-pair (a, b), a <= b, from blockIdx.x (block-uniform scalar loop).
    int p = blockIdx.x;
    int a = 0;
    while (p >= NT - a) { p -= NT - a; ++a; }
    const int b = a + p;

    const int tid = threadIdx.x;

    // Stage the 32-j chunk of tile b into LDS.
    if (tid < JC) {
        const int j  = b * TILE + blockIdx.y * JC + tid;
        const int yj = j / WW;
        const float fy = (float)yj;
        const float fx = (float)(j - yj * WW);
        const float r  = image[j];
        const float g  = image[NN + j];
        const float bl = image[2 * NN + j];
        const float aj = probs[j];
        const float Aj = -CXY * fmaf(fy, fy, fx * fx)
                         - CRGB * fmaf(r, r, fmaf(g, g, bl * bl));
        sq1[tid] = make_float4(2.0f * CXY * fy, 2.0f * CXY * fx,
                               2.0f * CRGB * r, 2.0f * CRGB * g);
        sq2[tid] = make_float4(2.0f * CRGB * bl, Aj, aj, 0.0f);
    }

    // Per-thread i data: M coalesced i's from tile a.
    float yi[M], xi[M], ri[M], gi[M], bi[M], ai[M], ci[M], Ai[M], acc[M];
#pragma unroll
    for (int m = 0; m < M; ++m) {
        const int i  = a * TILE + m * BLK + tid;
        const int yy = i / WW;
        yi[m] = (float)yy;
        xi[m] = (float)(i - yy * WW);
        ri[m] = image[i];
        gi[m] = image[NN + i];
        bi[m] = image[2 * NN + i];
        ai[m] = probs[i];
        ci[m] = fmaf(-2.0f, ai[m], 1.0f);   // 1 - 2*ai
        Ai[m] = -CXY * fmaf(yi[m], yi[m], xi[m] * xi[m])
                - CRGB * fmaf(ri[m], ri[m], fmaf(gi[m], gi[m], bi[m] * bi[m]));
        acc[m] = 0.0f;
    }

    __syncthreads();

#pragma unroll 4
    for (int t = 0; t < JC; ++t) {
        const float4 q1 = sq1[t];   // broadcast, conflict-free (ds_read_b128)
        const float4 q2 = sq2[t];
#pragma unroll
        for (int m = 0; m < M; ++m) {
            float arg = Ai[m] + q2.y;
            arg = fmaf(yi[m], q1.x, arg);
            arg = fmaf(xi[m], q1.y, arg);
            arg = fmaf(ri[m], q1.z, arg);
            arg = fmaf(gi[m], q1.w, arg);
            arg = fmaf(bi[m], q2.x, arg);
            const float k  = __builtin_amdgcn_exp2f(arg);
            const float wv = fmaf(q2.z, ci[m], ai[m]);  // ai + aj*(1-2ai)
            acc[m] = fmaf(wv, k, acc[m]);
        }
    }

    // Reduce: thread -> wave (64) -> block -> global atomic.
    float s = acc[0] + acc[1];
    for (int off = 32; off > 0; off >>= 1)
        s += __shfl_down(s, off, 64);

    __shared__ float wsum[BLK / 64];
    if ((tid & 63) == 0) wsum[tid >> 6] = s;
    __syncthreads();
    if (tid == 0) {
        float bs = 0.0f;
#pragma unroll
        for (int w = 0; w < BLK / 64; ++w) bs += wsum[w];
        const float weight = (a == b) ? 1.0f : 2.0f;   // symmetry: off-diag counted twice
        atomicAdd(out, bs * (weight / (float)NN));
    }
}

extern "C" void kernel_launch(void* const* d_in, const int* in_sizes, int n_in,
                              void* d_out, int out_size, void* d_ws, size_t ws_size,
                              hipStream_t stream) {
    const float* probs = (const float*)d_in[0];  // [1,2,96,96] fp32
    const float* image = (const float*)d_in[1];  // [1,3,96,96] fp32
    float* out = (float*)d_out;                  // [1] fp32

    // d_out is poisoned (0xAA) before every timed launch — zero it on-stream.
    hipMemsetAsync(out, 0, sizeof(float), stream);

    dim3 grid(NPAIRS, JSPLIT);   // 171 x 16 = 2736 blocks, 10944 waves
    crf_occ_kernel<<<grid, dim3(BLK), 0, stream>>>(probs, image, out);
}

// Round 6
// 71.096 us; speedup vs baseline: 1.3050x; 1.3050x over previous
//
#include <hip/hip_runtime.h>

#define HH 96
#define WW 96
#define NN (HH * WW)            // 9216
#define TILE 1024               // i/j tile size (proven best, R1)
#define NT (NN / TILE)          // 9 tiles
#define NPAIRS (NT * (NT + 1) / 2)  // 45 tile-pairs (a <= b)
#define JSPLIT 32
#define JC (TILE / JSPLIT)      // 32 j's per block
#define BLK 256
#define M 4                     // i's per thread -> i-tile = M*BLK = 1024
#define NPART (NPAIRS * JSPLIT) // 1440 partial sums

// Gaussian constants with log2(e) folded in (native v_exp_f32 is exp2):
// CXY  = log2(e) / (2 * 15^2),  CRGB = log2(e) / (2 * 0.125^2)
#define CXY 0.0032059890f
#define CRGB 46.16624131f

// arg_ij = Ai + Aj + yi*(2CXY*yj) + xi*(2CXY*xj) + ri*(2CRGB*rj) + gi*(2CRGB*gj) + bi*(2CRGB*bj)
// A_k = -CXY*(y^2+x^2) - CRGB*(r^2+g^2+b^2). All cross terms >= 0; the fma chain
// rises monotonically from Ai+Aj (>= -392) to <= 0: no overflow.
// Scalar form (packing regressed twice: R2 asm, R3 v2f).
// NO single-address atomics: each block stores its own partial (R4 post-mortem:
// serialized ~14 ns/atomic RMW on one address was the critical path).

__global__ __launch_bounds__(BLK) void crf_main_kernel(
    const float* __restrict__ probs,   // [2, N], class-0 plane first
    const float* __restrict__ image,   // [3, N]
    float* __restrict__ partials)      // [NPART]
{
    __shared__ float4 sq1[JC];  // (2CXY*yj, 2CXY*xj, 2CRGB*rj, 2CRGB*gj)
    __shared__ float4 sq2[JC];  // (2CRGB*bl, Aj, aj, pad)

    // Decode tile-pair (a, b), a <= b, from blockIdx.x (block-uniform scalar loop).
    int p = blockIdx.x;
    int a = 0;
    while (p >= NT - a) { p -= NT - a; ++a; }
    const int b = a + p;

    const int tid = threadIdx.x;

    // Stage the 32-j chunk of tile b into LDS.
    if (tid < JC) {
        const int j  = b * TILE + blockIdx.y * JC + tid;
        const int yj = j / WW;
        const float fy = (float)yj;
        const float fx = (float)(j - yj * WW);
        const float r  = image[j];
        const float g  = image[NN + j];
        const float bl = image[2 * NN + j];
        const float aj = probs[j];
        const float Aj = -CXY * fmaf(fy, fy, fx * fx)
                         - CRGB * fmaf(r, r, fmaf(g, g, bl * bl));
        sq1[tid] = make_float4(2.0f * CXY * fy, 2.0f * CXY * fx,
                               2.0f * CRGB * r, 2.0f * CRGB * g);
        sq2[tid] = make_float4(2.0f * CRGB * bl, Aj, aj, 0.0f);
    }

    // Per-thread i data: M coalesced i's from tile a.
    float yi[M], xi[M], ri[M], gi[M], bi[M], ai[M], ci[M], Ai[M], acc[M];
#pragma unroll
    for (int m = 0; m < M; ++m) {
        const int i  = a * TILE + m * BLK + tid;
        const int yy = i / WW;
        yi[m] = (float)yy;
        xi[m] = (float)(i - yy * WW);
        ri[m] = image[i];
        gi[m] = image[NN + i];
        bi[m] = image[2 * NN + i];
        ai[m] = probs[i];
        ci[m] = fmaf(-2.0f, ai[m], 1.0f);   // 1 - 2*ai
        Ai[m] = -CXY * fmaf(yi[m], yi[m], xi[m] * xi[m])
                - CRGB * fmaf(ri[m], ri[m], fmaf(gi[m], gi[m], bi[m] * bi[m]));
        acc[m] = 0.0f;
    }

    __syncthreads();

#pragma unroll 4
    for (int t = 0; t < JC; ++t) {
        const float4 q1 = sq1[t];   // broadcast, conflict-free (ds_read_b128)
        const float4 q2 = sq2[t];
#pragma unroll
        for (int m = 0; m < M; ++m) {
            float arg = Ai[m] + q2.y;
            arg = fmaf(yi[m], q1.x, arg);
            arg = fmaf(xi[m], q1.y, arg);
            arg = fmaf(ri[m], q1.z, arg);
            arg = fmaf(gi[m], q1.w, arg);
            arg = fmaf(bi[m], q2.x, arg);
            const float k  = __builtin_amdgcn_exp2f(arg);
            const float wv = fmaf(q2.z, ci[m], ai[m]);  // ai + aj*(1-2ai)
            acc[m] = fmaf(wv, k, acc[m]);
        }
    }

    // Reduce: thread -> wave (64) -> block -> private partial slot (no atomics).
    float s = (acc[0] + acc[1]) + (acc[2] + acc[3]);
    for (int off = 32; off > 0; off >>= 1)
        s += __shfl_down(s, off, 64);

    __shared__ float wsum[BLK / 64];
    if ((tid & 63) == 0) wsum[tid >> 6] = s;
    __syncthreads();
    if (tid == 0) {
        float bs = 0.0f;
#pragma unroll
        for (int w = 0; w < BLK / 64; ++w) bs += wsum[w];
        const float weight = (a == b) ? 1.0f : 2.0f;   // symmetry: off-diag counted twice
        partials[blockIdx.x * JSPLIT + blockIdx.y] = bs * weight;
    }
}

__global__ __launch_bounds__(BLK) void crf_finalize_kernel(
    const float* __restrict__ partials,  // [NPART]
    float* __restrict__ out)             // [1]
{
    const int tid = threadIdx.x;
    float s = 0.0f;
    for (int t = tid; t < NPART; t += BLK)
        s += partials[t];
    for (int off = 32; off > 0; off >>= 1)
        s += __shfl_down(s, off, 64);

    __shared__ float wsum[BLK / 64];
    if ((tid & 63) == 0) wsum[tid >> 6] = s;
    __syncthreads();
    if (tid == 0) {
        float bs = 0.0f;
#pragma unroll
        for (int w = 0; w < BLK / 64; ++w) bs += wsum[w];
        out[0] = bs * (1.0f / (float)NN);
    }
}

extern "C" void kernel_launch(void* const* d_in, const int* in_sizes, int n_in,
                              void* d_out, int out_size, void* d_ws, size_t ws_size,
                              hipStream_t stream) {
    const float* probs = (const float*)d_in[0];  // [1,2,96,96] fp32
    const float* image = (const float*)d_in[1];  // [1,3,96,96] fp32
    float* out = (float*)d_out;                  // [1] fp32
    float* partials = (float*)d_ws;              // NPART floats of scratch

    dim3 grid(NPAIRS, JSPLIT);   // 45 x 32 = 1440 blocks, 5760 waves
    crf_main_kernel<<<grid, dim3(BLK), 0, stream>>>(probs, image, partials);
    crf_finalize_kernel<<<dim3(1), dim3(BLK), 0, stream>>>(partials, out);
}